// Round 5
// baseline (683.075 us; speedup 1.0000x reference)
//
#include <hip/hip_runtime.h>
#include <hip/hip_bf16.h>
#include <cstdint>
#include <cstddef>

using u16 = unsigned short;
using u32 = unsigned int;

typedef __attribute__((ext_vector_type(8))) __bf16 bf16x8;
typedef __attribute__((ext_vector_type(4))) float f32x4;
typedef __attribute__((ext_vector_type(2))) float f32x2;
typedef __attribute__((ext_vector_type(4))) u32 u32x4;

typedef const __attribute__((address_space(1))) void* gas_ptr;
typedef __attribute__((address_space(3))) void* las_ptr;

__device__ __forceinline__ void async_cp16(const void* g, void* l) {
  __builtin_amdgcn_global_load_lds((gas_ptr)g, (las_ptr)l, 16, 0, 0);
}

__device__ __forceinline__ float bf2f(u16 u) {
  u32 v = ((u32)u) << 16;
  return __builtin_bit_cast(float, v);
}
__device__ __forceinline__ u16 f2bf(float f) {
  u32 v = __builtin_bit_cast(u32, f);
  u32 r = (v + 0x7fffu + ((v >> 16) & 1u)) >> 16;  // RNE
  return (u16)r;
}

__device__ __forceinline__ f32x4 mfma16(bf16x8 a, bf16x8 b, f32x4 c) {
  return __builtin_amdgcn_mfma_f32_16x16x32_bf16(a, b, c, 0, 0, 0);
}

// ---------------------------------------------------------------- convert
__global__ __launch_bounds__(256) void cvt_f32_bf16(const float* __restrict__ in,
                                                    u16* __restrict__ out, int n8) {
  int i = blockIdx.x * blockDim.x + threadIdx.x;
  int stride = gridDim.x * blockDim.x;
  for (; i < n8; i += stride) {
    const float4* p = (const float4*)(in + (size_t)i * 8);
    float4 a = p[0], b = p[1];
    union { u16 us[8]; u32x4 v; } o;
    o.us[0] = f2bf(a.x); o.us[1] = f2bf(a.y); o.us[2] = f2bf(a.z); o.us[3] = f2bf(a.w);
    o.us[4] = f2bf(b.x); o.us[5] = f2bf(b.y); o.us[6] = f2bf(b.z); o.us[7] = f2bf(b.w);
    *(u32x4*)(out + (size_t)i * 8) = o.v;
  }
}

// ---------------------------------------------------------------- GEMM C = A * B^T
// A-direct variant: A fragments load straight from global (16 rows x 64B fully
// used segments; wave pairs share rows -> L1 hits). LDS carries only B,
// double-buffered (2 x 16 KB), BK=64. A-frags register-prefetched one iter
// ahead (ping-pong). 1D grid, XCD strip swizzle.
template <bool F32OUT>
__global__ __launch_bounds__(256, 2) void gemm_bt(const u16* __restrict__ A,
                                                  const u16* __restrict__ B,
                                                  void* __restrict__ Cv,
                                                  int M, int N, int K) {
  __shared__ __align__(16) u16 Bs[2][128 * 64];
  const int tid = threadIdx.x;
  const int wave = tid >> 6, lane = tid & 63;
  const int quad = lane >> 4, c16 = lane & 15;

  const int mb = M >> 7, nb = N >> 7;
  const int per_xcd_n = nb >> 3;
  const int xcd = blockIdx.x & 7, lid = blockIdx.x >> 3;
  const int m_t = lid % mb, n_local = lid / mb;
  const int m0 = m_t * 128, n0 = (xcd * per_xcd_n + n_local) * 128;

  const int wm = (wave & 1) * 64, wn = (wave >> 1) * 64;

  f32x4 acc[4][4] = {};

  const u16* Bb = B + (size_t)n0 * K;
  const u16* Aw = A + (size_t)(m0 + wm + c16) * K + quad * 8;

  auto stageB = [&](int k0, int b) __attribute__((always_inline)) {
#pragma unroll
    for (int i = 0; i < 4; ++i) {
      int idx = tid + 256 * i;  // 1024 chunks = 128 rows x 8 segs
      int row = idx >> 3, sg = (idx & 7) ^ (row & 7);
      async_cp16(Bb + (size_t)row * K + k0 + sg * 8, &Bs[b][(size_t)idx * 8]);
    }
  };

  bf16x8 afA[4][2], afB[4][2];
  auto loadA = [&](int k0, bf16x8(&dst)[4][2]) __attribute__((always_inline)) {
#pragma unroll
    for (int mt = 0; mt < 4; ++mt)
#pragma unroll
      for (int c = 0; c < 2; ++c)
        dst[mt][c] = *(const bf16x8*)(Aw + (size_t)mt * 16 * K + k0 + c * 32);
  };

  stageB(0, 0);
  loadA(0, afA);

  auto kstep = [&](int k0, int cur, bf16x8(&au)[4][2], bf16x8(&ap)[4][2])
      __attribute__((always_inline)) {
    asm volatile("s_waitcnt vmcnt(0)" ::: "memory");
    __syncthreads();
    const bool more = (k0 + 64 < K);
    if (more) {
      stageB(k0 + 64, cur ^ 1);
      loadA(k0 + 64, ap);
    }
    bf16x8 bfr[4][2];
#pragma unroll
    for (int nt = 0; nt < 4; ++nt) {
      int row = wn + nt * 16 + c16;
#pragma unroll
      for (int c = 0; c < 2; ++c)
        bfr[nt][c] = *(const bf16x8*)(&Bs[cur][row * 64 + (((c * 4 + quad) ^ (row & 7)) * 8)]);
    }
#pragma unroll
    for (int c = 0; c < 2; ++c)
#pragma unroll
      for (int mt = 0; mt < 4; ++mt)
#pragma unroll
        for (int nt = 0; nt < 4; ++nt)
          acc[mt][nt] = mfma16(au[mt][c], bfr[nt][c], acc[mt][nt]);
  };

#pragma unroll 1
  for (int k0 = 0; k0 < K; k0 += 128) {
    kstep(k0, 0, afA, afB);
    kstep(k0 + 64, 1, afB, afA);
  }

#pragma unroll
  for (int mt = 0; mt < 4; ++mt) {
#pragma unroll
    for (int nt = 0; nt < 4; ++nt) {
#pragma unroll
      for (int r = 0; r < 4; ++r) {
        int gm = m0 + wm + mt * 16 + quad * 4 + r;
        int gn = n0 + wn + nt * 16 + c16;
        float v = acc[mt][nt][r];
        if (F32OUT)
          ((float*)Cv)[(size_t)gm * N + gn] = v;
        else
          ((u16*)Cv)[(size_t)gm * N + gn] = f2bf(v);
      }
    }
  }
}

// ---------------------------------------------------------------- V transpose
__global__ __launch_bounds__(256) void transpose_v(const u16* __restrict__ in,
                                                   u16* __restrict__ out) {
  __shared__ __align__(16) u16 t[64 * 72];
  const int bs = blockIdx.x * 64;
  const int be = blockIdx.y * 64;
  const int tid = threadIdx.x;
  {
    const int row = tid >> 3, cc = tid & 7;
#pragma unroll
    for (int pp = 0; pp < 2; ++pp) {
      int r = row + 32 * pp;
      u32x4 v = *(const u32x4*)(in + (size_t)(bs + r) * 6144 + 5120 + be + cc * 8);
      *(u32x4*)(&t[r * 72 + ((cc ^ ((r >> 3) & 7)) * 8)]) = v;
    }
  }
  __syncthreads();
  {
    const int c0 = tid >> 3, rc = tid & 7;
#pragma unroll
    for (int pp = 0; pp < 2; ++pp) {
      int c = c0 + 32 * pp;
      union { u16 us[8]; u32x4 v; } o;
#pragma unroll
      for (int j = 0; j < 8; ++j)
        o.us[j] = t[(rc * 8 + j) * 72 + ((((c >> 3) ^ rc) * 8) + (c & 7))];
      *(u32x4*)(out + (size_t)(be + c) * 2048 + bs + rc * 8) = o.v;
    }
  }
}

// ---------------------------------------------------------------- RoPE + RMSNorm
__global__ __launch_bounds__(256) void rope_rms(const u16* __restrict__ in, int stride,
                                                u16* __restrict__ out,
                                                const float* __restrict__ freqs,
                                                int n_heads) {
  int gw = blockIdx.x * 4 + (threadIdx.x >> 6);
  int lane = threadIdx.x & 63;
  int s = gw / n_heads, h = gw % n_heads;
  u32 ab = *(const u32*)(in + (size_t)s * stride + h * 128 + lane * 2);
  float a = bf2f((u16)(ab & 0xffff));
  float b = bf2f((u16)(ab >> 16));
  f32x2 ff = *(const f32x2*)(freqs + (size_t)s * 128 + lane * 2);
  float ra = a * ff.x - b * ff.y;
  float rb = a * ff.y + b * ff.x;
  float ss = ra * ra + rb * rb;
#pragma unroll
  for (int m = 32; m; m >>= 1) ss += __shfl_xor(ss, m, 64);
  float r = rsqrtf(ss * (1.0f / 128.0f) + 1e-5f);
  u32 pk = (u32)f2bf(ra * r) | ((u32)f2bf(rb * r) << 16);
  *(u32*)(out + ((size_t)h * 2048 + s) * 128 + lane * 2) = pk;
}

// ---------------------------------------------------------------- flash attention
#define SEQ 2048
__global__ __launch_bounds__(256) void attn(const u16* __restrict__ Q,
                                            const u16* __restrict__ Kh,
                                            const u16* __restrict__ VT,
                                            u16* __restrict__ O) {
  __shared__ __align__(16) u16 Ks[2][64 * 128];
  __shared__ __align__(16) u16 Vs[2][128 * 64];
  __shared__ __align__(16) u16 Ps[4][32 * 64];
  const int tid = threadIdx.x;
  const int wave = tid >> 6, lane = tid & 63;
  const int quad = lane >> 4, c16 = lane & 15;
  const int bid = blockIdx.x;
  const int hk = bid & 7;
  const int rest = bid >> 3;
  const int hq = rest >> 3;
  const int p = rest & 7;
  const int h = hk * 4 + hq;

  const float sc = 0.12751743f;  // log2(e)/sqrt(128)
  const float B = 16.5f;
  const u16* Kb = Kh + (size_t)hk * SEQ * 128;
  const u16* Vb = VT + (size_t)hk * 128 * SEQ;

  auto stage = [&](int t0, int b) __attribute__((always_inline)) {
#pragma unroll
    for (int i = 0; i < 4; ++i) {
      int idx = tid + 256 * i;
      int row = idx >> 4, sg = (idx & 15) ^ (row & 7);
      async_cp16(Kb + (size_t)(t0 + row) * 128 + sg * 8, &Ks[b][(size_t)idx * 8]);
    }
#pragma unroll
    for (int i = 0; i < 4; ++i) {
      int idx = tid + 256 * i;
      int row = idx >> 3, sg = (idx & 7) ^ (row & 7);
      async_cp16(Vb + (size_t)row * SEQ + t0 + sg * 8, &Vs[b][(size_t)idx * 8]);
    }
  };

#pragma unroll 1
  for (int tile = 0; tile < 2; ++tile) {
    const int qt = tile ? (15 - p) : p;
    const int q0w = qt * 128 + wave * 32;
    const int kend = qt * 128 + 128;

    bf16x8 qfr[2][4];
    const u16* qbase = Q + (size_t)h * SEQ * 128;
#pragma unroll
    for (int g = 0; g < 2; ++g)
#pragma unroll
      for (int c = 0; c < 4; ++c)
        qfr[g][c] =
            *(const bf16x8*)(qbase + (size_t)(q0w + g * 16 + c16) * 128 + c * 32 + quad * 8);

    f32x4 o_acc[2][8] = {};
    float lsum[2][4] = {};

    __syncthreads();
    stage(0, 0);

#pragma unroll 1
    for (int t0 = 0; t0 < kend; t0 += 64) {
      const int cur = (t0 >> 6) & 1;
      asm volatile("s_waitcnt vmcnt(0)" ::: "memory");
      __syncthreads();
      if (t0 + 64 < kend) stage(t0 + 64, cur ^ 1);

      if (t0 < q0w + 32) {
        f32x4 sa[2][4] = {};
#pragma unroll
        for (int ct = 0; ct < 4; ++ct) {
          int t = ct * 16 + c16;
          int tbase = t * 128;
          int tsw = t & 7;
#pragma unroll
          for (int c = 0; c < 4; ++c) {
            bf16x8 kf = *(const bf16x8*)(&Ks[cur][tbase + (((c * 4 + quad) ^ tsw) * 8)]);
            sa[0][ct] = mfma16(qfr[0][c], kf, sa[0][ct]);
            sa[1][ct] = mfma16(qfr[1][c], kf, sa[1][ct]);
          }
        }

        const bool diag = (t0 + 64 > q0w);
        auto soft = [&](bool masked) __attribute__((always_inline)) {
#pragma unroll
          for (int g = 0; g < 2; ++g) {
#pragma unroll
            for (int r = 0; r < 4; ++r) {
              int row = g * 16 + quad * 4 + r;
              int row_q = q0w + row;
              int rbase = row * 64;
              int rsw = row & 7;
#pragma unroll
              for (int ct = 0; ct < 4; ++ct) {
                float s = sa[g][ct][r];
                float arg = fmaf(s, sc, -B);
                if (masked) {
                  int t_idx = t0 + ct * 16 + c16;
                  arg = (t_idx <= row_q) ? arg : -1.0e30f;
                }
                float pe = exp2f(arg);
                lsum[g][r] += pe;
                u32 pb = (__builtin_bit_cast(u32, pe) + 0x8000u) >> 16;
                Ps[wave][rbase + (((ct * 2 + (c16 >> 3)) ^ rsw) * 8) + (c16 & 7)] = (u16)pb;
              }
            }
          }
        };
        if (diag) soft(true); else soft(false);
        asm volatile("s_waitcnt lgkmcnt(0)" ::: "memory");

#pragma unroll
        for (int tc = 0; tc < 2; ++tc) {
          bf16x8 pf[2];
#pragma unroll
          for (int g = 0; g < 2; ++g) {
            int prow = g * 16 + c16;
            pf[g] = *(const bf16x8*)(&Ps[wave][prow * 64 + (((tc * 4 + quad) ^ (prow & 7)) * 8)]);
          }
#pragma unroll
          for (int nt = 0; nt < 8; ++nt) {
            int dl = nt * 16 + c16;
            bf16x8 vf = *(const bf16x8*)(&Vs[cur][dl * 64 + (((tc * 4 + quad) ^ (dl & 7)) * 8)]);
            o_acc[0][nt] = mfma16(pf[0], vf, o_acc[0][nt]);
            o_acc[1][nt] = mfma16(pf[1], vf, o_acc[1][nt]);
          }
        }
      }
    }

#pragma unroll
    for (int g = 0; g < 2; ++g) {
#pragma unroll
      for (int r = 0; r < 4; ++r) {
        float l = lsum[g][r];
#pragma unroll
        for (int m = 1; m < 16; m <<= 1) l += __shfl_xor(l, m, 64);
        float inv = 1.0f / l;
        int s_idx = q0w + g * 16 + quad * 4 + r;
        u16* ob = O + (size_t)s_idx * 4096 + (size_t)h * 128;
#pragma unroll
        for (int nt = 0; nt < 8; ++nt) ob[nt * 16 + c16] = f2bf(o_acc[g][nt][r] * inv);
      }
    }
  }
}

// ---------------------------------------------------------------- launch
extern "C" void kernel_launch(void* const* d_in, const int* in_sizes, int n_in,
                              void* d_out, int out_size, void* d_ws, size_t ws_size,
                              hipStream_t stream) {
  const float* x  = (const float*)d_in[0];
  const float* wq = (const float*)d_in[1];
  const float* wk = (const float*)d_in[2];
  const float* wv = (const float*)d_in[3];
  const float* wo = (const float*)d_in[4];
  const float* fr = (const float*)d_in[5];
  float* out = (float*)d_out;

  const size_t S = 2048, D = 4096, KV = 1024, NQKV = D + 2 * KV;  // 6144
  u16* p = (u16*)d_ws;
  u16* xb     = p; p += S * D;
  u16* wqkv   = p; p += NQKV * D;
  u16* qkvraw = p; p += S * NQKV;
  u16* qh     = p; p += S * D;
  u16* khh    = p; p += S * KV;
  u16* vt     = p; p += KV * S;
  u16* wob = wqkv;
  u16* ob  = qkvraw;

  auto cvt_launch = [&](const float* src, u16* dst, size_t n) {
    int n8 = (int)(n / 8);
    int blocks = (n8 + 255) / 256;
    if (blocks > 2048) blocks = 2048;
    cvt_f32_bf16<<<dim3(blocks), dim3(256), 0, stream>>>(src, dst, n8);
  };

  cvt_launch(x, xb, S * D);
  cvt_launch(wq, wqkv, D * D);
  cvt_launch(wk, wqkv + D * D, KV * D);
  cvt_launch(wv, wqkv + (D + KV) * D, KV * D);

  // fused QKV GEMM: (2048 x 6144) = xb @ wqkv^T, 768 blocks (1D, XCD-swizzled)
  gemm_bt<false><<<dim3((S / 128) * (NQKV / 128)), dim3(256), 0, stream>>>(
      xb, wqkv, (void*)qkvraw, (int)S, (int)NQKV, (int)D);

  cvt_launch(wo, wob, D * D);

  transpose_v<<<dim3(32, 16), dim3(256), 0, stream>>>(qkvraw, vt);
  rope_rms<<<dim3((int)(S * 32 / 4)), dim3(256), 0, stream>>>(qkvraw, (int)NQKV, qh, fr, 32);
  rope_rms<<<dim3((int)(S * 8 / 4)), dim3(256), 0, stream>>>(qkvraw + D, (int)NQKV, khh, fr, 8);

  attn<<<dim3(256), dim3(256), 0, stream>>>(qh, khh, vt, ob);

  gemm_bt<true><<<dim3((S / 128) * (D / 128)), dim3(256), 0, stream>>>(
      ob, wob, (void*)out, (int)S, (int)D, (int)D);
}